// Round 5
// baseline (326.734 us; speedup 1.0000x reference)
//
#include <hip/hip_runtime.h>
#include <stdint.h>

#define NB 8192
#define DD 256

typedef unsigned short ushort_t;
typedef __attribute__((ext_vector_type(8))) short bf16x8;
typedef __attribute__((ext_vector_type(4))) float f32x4;

// ==================== workspace layout (8814592 B <= proven 10092544) ====================
#define OFF_DIAG   0          // f32[8192]
#define OFF_NEG    32768      // int[8192]
#define OFF_BAND   65536      // int[8192]
#define OFF_FBROWS 98304      // int[8192]
#define OFF_ACC    131072     // f32 acc @ +0, int fbcount @ +4
#define OFF_W1T    163840     // bf16[256][512]  (256 KB, swizzled)
#define OFF_TB     425984     // bf16[8192][256] (4 MB, swizzled)
#define OFF_VB     4620288    // bf16[8192][256] (4 MB, swizzled) -> end 8814592

__device__ __forceinline__ unsigned short f2bf(float x) {
    uint32_t u = __float_as_uint(x);
    return (unsigned short)((u + 0x7FFFu + ((u >> 16) & 1u)) >> 16);
}

__device__ __forceinline__ uint4 packbf8(float4 x, float4 y) {
    uint4 o;
    o.x = (uint32_t)f2bf(x.x) | ((uint32_t)f2bf(x.y) << 16);
    o.y = (uint32_t)f2bf(x.z) | ((uint32_t)f2bf(x.w) << 16);
    o.z = (uint32_t)f2bf(y.x) | ((uint32_t)f2bf(y.y) << 16);
    o.w = (uint32_t)f2bf(y.z) | ((uint32_t)f2bf(y.w) << 16);
    return o;
}

// ---------------- prep_uni: cvt(tuni), cvt(vuni) [swizzled], diag + band init ----------------
// Swizzle: out[row][kb*64 + c*8 + j] = in[row][kb*64 + (c^(row&7))*8 + j]
__global__ __launch_bounds__(256) void prep_uni_kernel(const float* __restrict__ t,
                                                       const float* __restrict__ v,
                                                       ushort_t* __restrict__ tb,
                                                       ushort_t* __restrict__ vb,
                                                       float* __restrict__ diag,
                                                       int* __restrict__ band) {
    const int b = blockIdx.x;
    if (b < 2048) {
        const float* in = (b < 1024) ? t : v;
        ushort_t* out = (b < 1024) ? tb : vb;
        int i = (b & 1023) * 256 + threadIdx.x;     // chunk id, 0..262143
        int row = i >> 5, cw = i & 31, kb = cw >> 3, c = cw & 7;
        int csrc = c ^ (row & 7);
        const float4* src = (const float4*)(in + (size_t)row * DD + kb * 64 + csrc * 8);
        ((uint4*)out)[i] = packbf8(src[0], src[1]);
    } else {
        int row = (b - 2048) * 4 + (threadIdx.x >> 6);
        int lane = threadIdx.x & 63;
        float4 a = *(const float4*)(t + (size_t)row * DD + lane * 4);
        float4 bb = *(const float4*)(v + (size_t)row * DD + lane * 4);
        float s = a.x * bb.x + a.y * bb.y + a.z * bb.z + a.w * bb.w;
        #pragma unroll
        for (int off = 32; off; off >>= 1) s += __shfl_down(s, off);
        if (lane == 0) diag[row] = s;
        if (lane == 1) band[row] = 0x7F7F7F7F;
    }
}

// ---------------- MFMA mining kernel (lite epilogue, swizzled LDS) ----------------
__device__ __forceinline__ void stage_tiles(const ushort_t* __restrict__ TB,
                                            const ushort_t* __restrict__ VB,
                                            ushort_t* As, ushort_t* Bs,
                                            int rowBase, int colBase, int kc, int tid) {
    #pragma unroll
    for (int i = 0; i < 4; ++i) {
        int idx = i * 256 + tid;              // 0..1023
        int r = idx >> 3, c8 = idx & 7;       // sources pre-swizzled -> linear copy
        __builtin_amdgcn_global_load_lds(
            (const __attribute__((address_space(1))) uint32_t*)(TB + (size_t)(rowBase + r) * DD + kc + c8 * 8),
            (__attribute__((address_space(3))) uint32_t*)(As + idx * 8), 16, 0, 0);
        __builtin_amdgcn_global_load_lds(
            (const __attribute__((address_space(1))) uint32_t*)(VB + (size_t)(colBase + r) * DD + kc + c8 * 8),
            (__attribute__((address_space(3))) uint32_t*)(Bs + idx * 8), 16, 0, 0);
    }
}

__global__ __launch_bounds__(256) void mine2_kernel(const ushort_t* __restrict__ TB,
                                                    const ushort_t* __restrict__ VB,
                                                    const float* __restrict__ diag,
                                                    int* __restrict__ band) {
    __shared__ ushort_t As[2][128 * 64];
    __shared__ ushort_t Bs[2][128 * 64];
    __shared__ float diag_s[128];

    const int tid = threadIdx.x;
    const int rowBase = blockIdx.x * 128;
    const int colGroup = blockIdx.y;
    const int lane = tid & 63;
    const int wave = tid >> 6;
    const int wr = wave >> 1, wc = wave & 1;
    const int lo = lane & 15, hi = lane >> 4;
    const int lx = lo & 7;                     // read-side chunk XOR (constant per lane)

    if (tid < 128) diag_s[tid] = diag[rowBase + tid];
    __syncthreads();

    float blo[4][4], bhi[4][4];
    #pragma unroll
    for (int m = 0; m < 4; m++)
        #pragma unroll
        for (int q = 0; q < 4; q++) {
            float d = diag_s[wr * 64 + m * 16 + hi * 4 + q];
            blo[m][q] = d - 0.5f;
            bhi[m][q] = d - 0.2f;
        }

    int bminR[4][4];
    #pragma unroll
    for (int m = 0; m < 4; m++)
        #pragma unroll
        for (int q = 0; q < 4; q++) bminR[m][q] = 0x7FFFFFFF;

    for (int ct = 0; ct < 4; ++ct) {
        const int colBase = colGroup * 512 + ct * 128;
        f32x4 acc[4][4];
        #pragma unroll
        for (int m = 0; m < 4; m++)
            #pragma unroll
            for (int n = 0; n < 4; n++) acc[m][n] = (f32x4){0.f, 0.f, 0.f, 0.f};

        stage_tiles(TB, VB, As[0], Bs[0], rowBase, colBase, 0, tid);
        __syncthreads();

        for (int kt = 0; kt < 4; ++kt) {
            const int buf = kt & 1;
            if (kt < 3)
                stage_tiles(TB, VB, As[buf ^ 1], Bs[buf ^ 1], rowBase, colBase, (kt + 1) * 64, tid);
            #pragma unroll
            for (int ksl = 0; ksl < 2; ksl++) {
                const int ch = (((ksl << 2) | hi) ^ lx) * 8;
                bf16x8 a[4], b[4];
                #pragma unroll
                for (int m = 0; m < 4; m++)
                    a[m] = *(const bf16x8*)&As[buf][(wr * 64 + m * 16 + lo) * 64 + ch];
                #pragma unroll
                for (int n = 0; n < 4; n++)
                    b[n] = *(const bf16x8*)&Bs[buf][(wc * 64 + n * 16 + lo) * 64 + ch];
                #pragma unroll
                for (int m = 0; m < 4; m++)
                    #pragma unroll
                    for (int n = 0; n < 4; n++)
                        acc[m][n] = __builtin_amdgcn_mfma_f32_16x16x32_bf16(a[m], b[n], acc[m][n], 0, 0, 0);
            }
            __syncthreads();
        }

        // lite epilogue: band-min only, kept in registers across ct
        #pragma unroll
        for (int m = 0; m < 4; m++)
            #pragma unroll
            for (int q = 0; q < 4; q++) {
                const float lo_b = blo[m][q], hi_b = bhi[m][q];
                #pragma unroll
                for (int n = 0; n < 4; n++) {
                    const float s = acc[m][n][q];
                    const int gcol = colBase + wc * 64 + n * 16 + lo;
                    int cand = (s > lo_b && s < hi_b) ? gcol : 0x7FFFFFFF;
                    bminR[m][q] = min(bminR[m][q], cand);
                }
            }
    }

    #pragma unroll
    for (int m = 0; m < 4; m++)
        #pragma unroll
        for (int q = 0; q < 4; q++) {
            int bm = bminR[m][q];
            #pragma unroll
            for (int off = 1; off < 16; off <<= 1) bm = min(bm, __shfl_xor(bm, off));
            if (lo == 0 && bm != 0x7FFFFFFF)
                atomicMin(&band[rowBase + wr * 64 + m * 16 + hi * 4 + q], bm);
        }
}

// ---------------- combine: neg from band; collect fallback rows ----------------
__global__ __launch_bounds__(256) void combine3_kernel(const int* __restrict__ band,
                                                       int* __restrict__ neg,
                                                       int* __restrict__ fbrows,
                                                       int* __restrict__ fbcount) {
    int row = blockIdx.x * 256 + threadIdx.x;
    int v = band[row];
    if (v < NB) {
        neg[row] = v;
    } else {
        neg[row] = 0;                       // placeholder; fixup overwrites
        int i = atomicAdd(fbcount, 1);
        fbrows[i] = row;
    }
}

// ---------------- fixup: exact off-diag argmax for empty-band rows (expected: none) ----------------
__global__ __launch_bounds__(256) void fixup_kernel(const float* __restrict__ tuni,
                                                    const float* __restrict__ vuni,
                                                    const int* __restrict__ fbrows,
                                                    const int* __restrict__ fbcount,
                                                    int* __restrict__ neg) {
    __shared__ float tL[256];
    __shared__ float sv[256];
    __shared__ int sc[256];
    const int count = fbcount[0];
    const int tid = threadIdx.x;
    for (int li = blockIdx.x; li < count; li += 64) {
        const int row = fbrows[li];
        __syncthreads();
        tL[tid] = tuni[(size_t)row * DD + tid];
        __syncthreads();
        float best = -1e30f; int bc = 0;
        for (int base = 0; base < NB; base += 256) {
            int col = base + tid;
            const float* vr = vuni + (size_t)col * DD;
            float d = 0.f;
            for (int k = 0; k < DD; k++) d += tL[k] * vr[k];
            if (col != row && (d > best || (d == best && col < bc))) { best = d; bc = col; }
        }
        sv[tid] = best; sc[tid] = bc;
        __syncthreads();
        for (int s = 128; s; s >>= 1) {
            if (tid < s) {
                if (sv[tid + s] > sv[tid] || (sv[tid + s] == sv[tid] && sc[tid + s] < sc[tid])) {
                    sv[tid] = sv[tid + s]; sc[tid] = sc[tid + s];
                }
            }
            __syncthreads();
        }
        if (tid == 0) neg[row] = sc[0];
    }
}

// ---------------- prep_head: cvt(tcross), cvt(vcross) [swizzled], W1 transpose+cvt [swizzled] ----------------
__global__ __launch_bounds__(256) void prep_head_kernel(const float* __restrict__ tcross,
                                                        const float* __restrict__ vcross,
                                                        const float* __restrict__ W1,
                                                        ushort_t* __restrict__ tb,
                                                        ushort_t* __restrict__ vb,
                                                        ushort_t* __restrict__ W1T) {
    const int b = blockIdx.x;
    const int tid = threadIdx.x;
    if (b < 2048) {
        const float* in = (b < 1024) ? tcross : vcross;
        ushort_t* out = (b < 1024) ? tb : vb;
        int i = (b & 1023) * 256 + tid;
        int row = i >> 5, cw = i & 31, kb = cw >> 3, c = cw & 7;
        int csrc = c ^ (row & 7);
        const float4* src = (const float4*)(in + (size_t)row * DD + kb * 64 + csrc * 8);
        ((uint4*)out)[i] = packbf8(src[0], src[1]);
    } else {
        // W1T[n][k] = bf16(W1[k][n]), k in [kb*64, kb*64+64), n in [nb*64, nb*64+64), chunk-swizzled by n&7
        __shared__ float Ls[64][68];
        int tt = b - 2048;                  // 0..31
        int kb = tt >> 2, nb = tt & 3;
        int r = tid >> 2, q4 = tid & 3;     // load: k-row r, 16-float chunk q4
        #pragma unroll
        for (int j = 0; j < 4; j++) {
            float4 x = *(const float4*)(W1 + (size_t)(kb * 64 + r) * DD + nb * 64 + q4 * 16 + j * 4);
            *(float4*)&Ls[r][q4 * 16 + j * 4] = x;
        }
        __syncthreads();
        int rn = tid >> 2, cq = (tid & 3) * 2;   // write: n-row rn, chunks cq, cq+1
        #pragma unroll
        for (int cc = 0; cc < 2; cc++) {
            int c = cq + cc;
            int csrc = c ^ (rn & 7);
            float4 x, y;
            x.x = Ls[csrc * 8 + 0][rn]; x.y = Ls[csrc * 8 + 1][rn];
            x.z = Ls[csrc * 8 + 2][rn]; x.w = Ls[csrc * 8 + 3][rn];
            y.x = Ls[csrc * 8 + 4][rn]; y.y = Ls[csrc * 8 + 5][rn];
            y.z = Ls[csrc * 8 + 6][rn]; y.w = Ls[csrc * 8 + 7][rn];
            *(uint4*)&W1T[(size_t)(nb * 64 + rn) * 512 + kb * 64 + c * 8] = packbf8(x, y);
        }
    }
}

// ==================== MFMA ITM head (dots inline) ====================
__device__ __forceinline__ void stage_head(const ushort_t* __restrict__ TCB,
                                           const ushort_t* __restrict__ VCB,
                                           const int* __restrict__ neg, int isNeg,
                                           const ushort_t* __restrict__ W1T,
                                           ushort_t* As, ushort_t* Bs,
                                           int rowBase, int kc, int tid) {
    #pragma unroll
    for (int i = 0; i < 2; ++i) {                 // A: 64 rows x 64 k
        int idx = i * 256 + tid;                  // 0..511
        int r = idx >> 3, c8 = idx & 7;
        const ushort_t* src;
        if (kc < 256) {
            src = TCB + (size_t)(rowBase + r) * DD + kc + c8 * 8;          // swizzle keys match (r&7)
        } else {
            int rr = isNeg ? neg[rowBase + r] : (rowBase + r);
            int cs = c8 ^ ((r ^ rr) & 7);                                   // re-key rr&7 -> r&7
            src = VCB + (size_t)rr * DD + (kc - 256) + cs * 8;
        }
        __builtin_amdgcn_global_load_lds(
            (const __attribute__((address_space(1))) uint32_t*)src,
            (__attribute__((address_space(3))) uint32_t*)(As + idx * 8), 16, 0, 0);
    }
    #pragma unroll
    for (int i = 0; i < 8; ++i) {                 // B: 256 cols x 64 k (W1T pre-swizzled)
        int idx = i * 256 + tid;                  // 0..2047
        int n = idx >> 3, c8 = idx & 7;
        __builtin_amdgcn_global_load_lds(
            (const __attribute__((address_space(1))) uint32_t*)(W1T + (size_t)n * 512 + kc + c8 * 8),
            (__attribute__((address_space(3))) uint32_t*)(Bs + idx * 8), 16, 0, 0);
    }
}

__global__ __launch_bounds__(256) void head2_kernel(const ushort_t* __restrict__ TCB,
                                                    const ushort_t* __restrict__ VCB,
                                                    const ushort_t* __restrict__ W1T,
                                                    const int* __restrict__ neg,
                                                    const float* __restrict__ tcf,
                                                    const float* __restrict__ vcf,
                                                    const float* __restrict__ W1,
                                                    const float* __restrict__ b1,
                                                    const float* __restrict__ W2,
                                                    const float* __restrict__ b2,
                                                    float* __restrict__ acc_out) {
    __shared__ ushort_t As[2][64 * 64];
    __shared__ ushort_t Bs[2][256 * 64];
    __shared__ float dot_l[64];
    __shared__ float logit_l[64];

    const int tid = threadIdx.x;
    const int rowBase = blockIdx.x * 64;
    const int isNeg = blockIdx.y;
    const int lane = tid & 63;
    const int wcv = tid >> 6;
    const int lo = lane & 15, hi = lane >> 4;
    const int lx = lo & 7;

    // inline dot feature (fp32 exact): 4 threads per row
    {
        int r = tid >> 2, quarter = tid & 3;
        int grow = rowBase + r;
        int vrow = isNeg ? neg[grow] : grow;
        const float4* tp = (const float4*)(tcf + (size_t)grow * DD + quarter * 64);
        const float4* vp = (const float4*)(vcf + (size_t)vrow * DD + quarter * 64);
        float sd = 0.f;
        #pragma unroll
        for (int j = 0; j < 16; j++) {
            float4 a = tp[j], v = vp[j];
            sd += a.x * v.x + a.y * v.y + a.z * v.z + a.w * v.w;
        }
        sd += __shfl_xor(sd, 1);
        sd += __shfl_xor(sd, 2);
        if (quarter == 0) dot_l[r] = sd;
        if (tid < 64) logit_l[tid] = 0.f;
    }

    f32x4 acc[4][4];
    #pragma unroll
    for (int m = 0; m < 4; m++)
        #pragma unroll
        for (int n = 0; n < 4; n++) acc[m][n] = (f32x4){0.f, 0.f, 0.f, 0.f};

    stage_head(TCB, VCB, neg, isNeg, W1T, As[0], Bs[0], rowBase, 0, tid);
    __syncthreads();

    for (int kt = 0; kt < 8; ++kt) {
        const int buf = kt & 1;
        if (kt < 7)
            stage_head(TCB, VCB, neg, isNeg, W1T, As[buf ^ 1], Bs[buf ^ 1], rowBase, (kt + 1) * 64, tid);
        #pragma unroll
        for (int ksl = 0; ksl < 2; ksl++) {
            const int ch = (((ksl << 2) | hi) ^ lx) * 8;
            bf16x8 a[4], b[4];
            #pragma unroll
            for (int m = 0; m < 4; m++)
                a[m] = *(const bf16x8*)&As[buf][(m * 16 + lo) * 64 + ch];
            #pragma unroll
            for (int n = 0; n < 4; n++)
                b[n] = *(const bf16x8*)&Bs[buf][(wcv * 64 + n * 16 + lo) * 64 + ch];
            #pragma unroll
            for (int m = 0; m < 4; m++)
                #pragma unroll
                for (int n = 0; n < 4; n++)
                    acc[m][n] = __builtin_amdgcn_mfma_f32_16x16x32_bf16(a[m], b[n], acc[m][n], 0, 0, 0);
        }
        __syncthreads();
    }

    // epilogue: +b1 +dot*W1[512], relu, @W2; reduce to logits
    float b1v[4], w5v[4], w2v[4];
    #pragma unroll
    for (int n = 0; n < 4; n++) {
        int cl = wcv * 64 + n * 16 + lo;
        b1v[n] = b1[cl];
        w5v[n] = W1[(size_t)512 * DD + cl];
        w2v[n] = W2[cl];
    }
    #pragma unroll
    for (int m = 0; m < 4; m++) {
        #pragma unroll
        for (int q = 0; q < 4; q++) {
            const int rl = m * 16 + hi * 4 + q;
            const float dt = dot_l[rl];
            float x = 0.f;
            #pragma unroll
            for (int n = 0; n < 4; n++) {
                float h = acc[m][n][q] + b1v[n] + dt * w5v[n];
                x += fmaxf(h, 0.f) * w2v[n];
            }
            #pragma unroll
            for (int off = 1; off < 16; off <<= 1) x += __shfl_xor(x, off);
            if (lo == 0) atomicAdd(&logit_l[rl], x);
        }
    }
    __syncthreads();

    if (tid < 64) {
        float x = logit_l[tid] + b2[0];
        float z = isNeg ? x : -x;                        // 1-sigmoid(x) = sigmoid(-x)
        float term = -logf(1.f / (1.f + expf(z)) + 1e-8f);
        #pragma unroll
        for (int off = 32; off; off >>= 1) term += __shfl_down(term, off);
        if (tid == 0) atomicAdd(acc_out, term);
    }
}

__global__ void finalize_kernel(const float* __restrict__ acc, float* __restrict__ out) {
    out[0] = acc[0] * (1.0f / (2.0f * (float)NB));
}

// ==================== launch ====================
extern "C" void kernel_launch(void* const* d_in, const int* in_sizes, int n_in,
                              void* d_out, int out_size, void* d_ws, size_t ws_size,
                              hipStream_t stream) {
    const float* vcross = (const float*)d_in[0];
    const float* tcross = (const float*)d_in[1];
    const float* vuni   = (const float*)d_in[2];
    const float* tuni   = (const float*)d_in[3];
    const float* W1     = (const float*)d_in[4];
    const float* b1     = (const float*)d_in[5];
    const float* W2     = (const float*)d_in[6];
    const float* b2     = (const float*)d_in[7];

    char* ws = (char*)d_ws;
    float* diag   = (float*)(ws + OFF_DIAG);
    int* neg      = (int*)(ws + OFF_NEG);
    int* band     = (int*)(ws + OFF_BAND);
    int* fbrows   = (int*)(ws + OFF_FBROWS);
    float* acc    = (float*)(ws + OFF_ACC);
    int* fbcount  = (int*)(ws + OFF_ACC + 4);
    ushort_t* w1t = (ushort_t*)(ws + OFF_W1T);
    ushort_t* tb  = (ushort_t*)(ws + OFF_TB);
    ushort_t* vb  = (ushort_t*)(ws + OFF_VB);

    hipMemsetAsync(ws + OFF_ACC, 0, 8, stream);     // acc + fbcount

    prep_uni_kernel<<<4096, 256, 0, stream>>>(tuni, vuni, tb, vb, diag, band);
    mine2_kernel<<<dim3(NB / 128, 16), 256, 0, stream>>>(tb, vb, diag, band);
    combine3_kernel<<<NB / 256, 256, 0, stream>>>(band, neg, fbrows, fbcount);
    fixup_kernel<<<64, 256, 0, stream>>>(tuni, vuni, fbrows, fbcount, neg);
    prep_head_kernel<<<2080, 256, 0, stream>>>(tcross, vcross, W1, tb, vb, w1t);
    head2_kernel<<<dim3(NB / 64, 2), 256, 0, stream>>>(tb, vb, w1t, neg, tcross, vcross,
                                                       W1, b1, W2, b2, acc);
    finalize_kernel<<<1, 1, 0, stream>>>(acc, (float*)d_out);
}

// Round 6
// 191.867 us; speedup vs baseline: 1.7029x; 1.7029x over previous
//
#include <hip/hip_runtime.h>
#include <stdint.h>

#define NB 8192
#define DD 256

typedef unsigned short ushort_t;
typedef __attribute__((ext_vector_type(8))) short bf16x8;
typedef __attribute__((ext_vector_type(4))) float f32x4;

// ==================== workspace layout ====================
#define OFF_DIAG   0          // f32[8192]
#define OFF_NEG    32768      // int[8192]
#define OFF_BAND   65536      // int[8192]
#define OFF_FBROWS 98304      // int[8192] (only first 64 used)
#define OFF_ACC    131072     // f32 acc @+0, int fbcount @+4, u64 fbbest[64] @+8
#define OFF_W1T    163840     // bf16[256][512]  (256 KB, swizzled)
#define OFF_TB     425984     // bf16[8192][256] (4 MB, swizzled)
#define OFF_VB     4620288    // bf16[8192][256] (4 MB, swizzled) -> end 8814592

__device__ __forceinline__ unsigned short f2bf(float x) {
    uint32_t u = __float_as_uint(x);
    return (unsigned short)((u + 0x7FFFu + ((u >> 16) & 1u)) >> 16);
}

__device__ __forceinline__ uint4 packbf8(float4 x, float4 y) {
    uint4 o;
    o.x = (uint32_t)f2bf(x.x) | ((uint32_t)f2bf(x.y) << 16);
    o.y = (uint32_t)f2bf(x.z) | ((uint32_t)f2bf(x.w) << 16);
    o.z = (uint32_t)f2bf(y.x) | ((uint32_t)f2bf(y.y) << 16);
    o.w = (uint32_t)f2bf(y.z) | ((uint32_t)f2bf(y.w) << 16);
    return o;
}

// order-preserving float->uint key
__device__ __forceinline__ unsigned fkey(float s) {
    unsigned u = __float_as_uint(s);
    return (u & 0x80000000u) ? ~u : (u | 0x80000000u);
}

// ---------------- prep_uni: cvt(tuni), cvt(vuni) [swizzled], diag + band init ----------------
__global__ __launch_bounds__(256) void prep_uni_kernel(const float* __restrict__ t,
                                                       const float* __restrict__ v,
                                                       ushort_t* __restrict__ tb,
                                                       ushort_t* __restrict__ vb,
                                                       float* __restrict__ diag,
                                                       int* __restrict__ band) {
    const int b = blockIdx.x;
    if (b < 2048) {
        const float* in = (b < 1024) ? t : v;
        ushort_t* out = (b < 1024) ? tb : vb;
        int i = (b & 1023) * 256 + threadIdx.x;     // chunk id, 0..262143
        int row = i >> 5, cw = i & 31, kb = cw >> 3, c = cw & 7;
        int csrc = c ^ (row & 7);
        const float4* src = (const float4*)(in + (size_t)row * DD + kb * 64 + csrc * 8);
        ((uint4*)out)[i] = packbf8(src[0], src[1]);
    } else {
        int row = (b - 2048) * 4 + (threadIdx.x >> 6);
        int lane = threadIdx.x & 63;
        float4 a = *(const float4*)(t + (size_t)row * DD + lane * 4);
        float4 bb = *(const float4*)(v + (size_t)row * DD + lane * 4);
        float s = a.x * bb.x + a.y * bb.y + a.z * bb.z + a.w * bb.w;
        #pragma unroll
        for (int off = 32; off; off >>= 1) s += __shfl_down(s, off);
        if (lane == 0) diag[row] = s;
        if (lane == 1) band[row] = 0x7F7F7F7F;
    }
}

// ---------------- MFMA mining kernel (lite epilogue, swizzled LDS) ----------------
__device__ __forceinline__ void stage_tiles(const ushort_t* __restrict__ TB,
                                            const ushort_t* __restrict__ VB,
                                            ushort_t* As, ushort_t* Bs,
                                            int rowBase, int colBase, int kc, int tid) {
    #pragma unroll
    for (int i = 0; i < 4; ++i) {
        int idx = i * 256 + tid;              // 0..1023
        int r = idx >> 3, c8 = idx & 7;       // sources pre-swizzled -> linear copy
        __builtin_amdgcn_global_load_lds(
            (const __attribute__((address_space(1))) uint32_t*)(TB + (size_t)(rowBase + r) * DD + kc + c8 * 8),
            (__attribute__((address_space(3))) uint32_t*)(As + idx * 8), 16, 0, 0);
        __builtin_amdgcn_global_load_lds(
            (const __attribute__((address_space(1))) uint32_t*)(VB + (size_t)(colBase + r) * DD + kc + c8 * 8),
            (__attribute__((address_space(3))) uint32_t*)(Bs + idx * 8), 16, 0, 0);
    }
}

__global__ __launch_bounds__(256) void mine2_kernel(const ushort_t* __restrict__ TB,
                                                    const ushort_t* __restrict__ VB,
                                                    const float* __restrict__ diag,
                                                    int* __restrict__ band) {
    __shared__ ushort_t As[2][128 * 64];
    __shared__ ushort_t Bs[2][128 * 64];
    __shared__ float diag_s[128];

    const int tid = threadIdx.x;
    const int rowBase = blockIdx.x * 128;
    const int colGroup = blockIdx.y;
    const int lane = tid & 63;
    const int wave = tid >> 6;
    const int wr = wave >> 1, wc = wave & 1;
    const int lo = lane & 15, hi = lane >> 4;
    const int lx = lo & 7;                     // read-side chunk XOR (constant per lane)

    if (tid < 128) diag_s[tid] = diag[rowBase + tid];
    __syncthreads();

    float mid[4][4];
    #pragma unroll
    for (int m = 0; m < 4; m++)
        #pragma unroll
        for (int q = 0; q < 4; q++)
            mid[m][q] = diag_s[wr * 64 + m * 16 + hi * 4 + q] - 0.35f;

    int bminR[4][4];
    #pragma unroll
    for (int m = 0; m < 4; m++)
        #pragma unroll
        for (int q = 0; q < 4; q++) bminR[m][q] = 0x7FFFFFFF;

    for (int ct = 0; ct < 4; ++ct) {
        const int colBase = colGroup * 512 + ct * 128;
        f32x4 acc[4][4];
        #pragma unroll
        for (int m = 0; m < 4; m++)
            #pragma unroll
            for (int n = 0; n < 4; n++) acc[m][n] = (f32x4){0.f, 0.f, 0.f, 0.f};

        stage_tiles(TB, VB, As[0], Bs[0], rowBase, colBase, 0, tid);
        __syncthreads();

        for (int kt = 0; kt < 4; ++kt) {
            const int buf = kt & 1;
            if (kt < 3)
                stage_tiles(TB, VB, As[buf ^ 1], Bs[buf ^ 1], rowBase, colBase, (kt + 1) * 64, tid);
            #pragma unroll
            for (int ksl = 0; ksl < 2; ksl++) {
                const int ch = (((ksl << 2) | hi) ^ lx) * 8;
                bf16x8 a[4], b[4];
                #pragma unroll
                for (int m = 0; m < 4; m++)
                    a[m] = *(const bf16x8*)&As[buf][(wr * 64 + m * 16 + lo) * 64 + ch];
                #pragma unroll
                for (int n = 0; n < 4; n++)
                    b[n] = *(const bf16x8*)&Bs[buf][(wc * 64 + n * 16 + lo) * 64 + ch];
                #pragma unroll
                for (int m = 0; m < 4; m++)
                    #pragma unroll
                    for (int n = 0; n < 4; n++)
                        acc[m][n] = __builtin_amdgcn_mfma_f32_16x16x32_bf16(a[m], b[n], acc[m][n], 0, 0, 0);
            }
            __syncthreads();
        }

        // lite epilogue: band-min only; |s-(d-0.35)| < 0.15 <=> d-0.5 < s < d-0.2
        #pragma unroll
        for (int m = 0; m < 4; m++)
            #pragma unroll
            for (int q = 0; q < 4; q++) {
                const float c0 = mid[m][q];
                #pragma unroll
                for (int n = 0; n < 4; n++) {
                    const float tt = acc[m][n][q] - c0;
                    const int gcol = colBase + wc * 64 + n * 16 + lo;
                    int cand = (fabsf(tt) < 0.15f) ? gcol : 0x7FFFFFFF;
                    bminR[m][q] = min(bminR[m][q], cand);
                }
            }
    }

    #pragma unroll
    for (int m = 0; m < 4; m++)
        #pragma unroll
        for (int q = 0; q < 4; q++) {
            int bm = bminR[m][q];
            #pragma unroll
            for (int off = 1; off < 16; off <<= 1) bm = min(bm, __shfl_xor(bm, off));
            if (lo == 0 && bm != 0x7FFFFFFF)
                atomicMin(&band[rowBase + wr * 64 + m * 16 + hi * 4 + q], bm);
        }
}

// ---------------- combine: neg from band; collect fallback rows (cap 64) ----------------
__global__ __launch_bounds__(256) void combine3_kernel(const int* __restrict__ band,
                                                       int* __restrict__ neg,
                                                       int* __restrict__ fbrows,
                                                       int* __restrict__ fbcount) {
    int row = blockIdx.x * 256 + threadIdx.x;
    int v = band[row];
    if (v < NB) {
        neg[row] = v;
    } else {
        neg[row] = (row + 4096) & (NB - 1);     // valid placeholder (overwritten by fixup_write)
        int i = atomicAdd(fbcount, 1);
        if (i < 64) fbrows[i] = row;
    }
}

// ---------------- fixup3: parallel off-diag argmax for empty-band rows ----------------
// grid (32 col-chunks, 64 row-slots); packed u64 atomicMax; tie-break = smallest col.
__global__ __launch_bounds__(256) void fixup3_kernel(const float* __restrict__ tuni,
                                                     const float* __restrict__ vuni,
                                                     const int* __restrict__ fbrows,
                                                     const int* __restrict__ fbcount,
                                                     unsigned long long* __restrict__ fbbest) {
    const int slot = blockIdx.y;
    const int count = min(fbcount[0], 64);
    if (slot >= count) return;
    const int row = fbrows[slot];
    const int tid = threadIdx.x;

    __shared__ float tL[DD];
    tL[tid] = tuni[(size_t)row * DD + tid];
    __syncthreads();

    const int col = blockIdx.x * 256 + tid;
    const float4* vr = (const float4*)(vuni + (size_t)col * DD);
    float d = 0.f;
    #pragma unroll 8
    for (int k4 = 0; k4 < 64; k4++) {
        float4 v = vr[k4];
        const float* tk = &tL[k4 * 4];
        d += v.x * tk[0] + v.y * tk[1] + v.z * tk[2] + v.w * tk[3];
    }
    if (col != row) {
        unsigned long long p = ((unsigned long long)fkey(d) << 32) | (unsigned)(NB - 1 - col);
        atomicMax(&fbbest[slot], p);
    }
}

__global__ void fixup_write_kernel(const int* __restrict__ fbrows,
                                   const int* __restrict__ fbcount,
                                   const unsigned long long* __restrict__ fbbest,
                                   int* __restrict__ neg) {
    int i = threadIdx.x;
    if (i < min(fbcount[0], 64))
        neg[fbrows[i]] = NB - 1 - (int)(unsigned)(fbbest[i] & 0xFFFFFFFFull);
}

// ---------------- prep_head: cvt(tcross), cvt(vcross) [swizzled], W1 transpose+cvt [swizzled] ----------------
__global__ __launch_bounds__(256) void prep_head_kernel(const float* __restrict__ tcross,
                                                        const float* __restrict__ vcross,
                                                        const float* __restrict__ W1,
                                                        ushort_t* __restrict__ tb,
                                                        ushort_t* __restrict__ vb,
                                                        ushort_t* __restrict__ W1T) {
    const int b = blockIdx.x;
    const int tid = threadIdx.x;
    if (b < 2048) {
        const float* in = (b < 1024) ? tcross : vcross;
        ushort_t* out = (b < 1024) ? tb : vb;
        int i = (b & 1023) * 256 + tid;
        int row = i >> 5, cw = i & 31, kb = cw >> 3, c = cw & 7;
        int csrc = c ^ (row & 7);
        const float4* src = (const float4*)(in + (size_t)row * DD + kb * 64 + csrc * 8);
        ((uint4*)out)[i] = packbf8(src[0], src[1]);
    } else {
        // W1T[n][k] = bf16(W1[k][n]), chunk-swizzled by n&7 within each 64-k block
        __shared__ float Ls[64][68];
        int tt = b - 2048;                  // 0..31
        int kb = tt >> 2, nb = tt & 3;
        int r = tid >> 2, q4 = tid & 3;
        #pragma unroll
        for (int j = 0; j < 4; j++) {
            float4 x = *(const float4*)(W1 + (size_t)(kb * 64 + r) * DD + nb * 64 + q4 * 16 + j * 4);
            *(float4*)&Ls[r][q4 * 16 + j * 4] = x;
        }
        __syncthreads();
        int rn = tid >> 2, cq = (tid & 3) * 2;
        #pragma unroll
        for (int cc = 0; cc < 2; cc++) {
            int c = cq + cc;
            int csrc = c ^ (rn & 7);
            float4 x, y;
            x.x = Ls[csrc * 8 + 0][rn]; x.y = Ls[csrc * 8 + 1][rn];
            x.z = Ls[csrc * 8 + 2][rn]; x.w = Ls[csrc * 8 + 3][rn];
            y.x = Ls[csrc * 8 + 4][rn]; y.y = Ls[csrc * 8 + 5][rn];
            y.z = Ls[csrc * 8 + 6][rn]; y.w = Ls[csrc * 8 + 7][rn];
            *(uint4*)&W1T[(size_t)(nb * 64 + rn) * 512 + kb * 64 + c * 8] = packbf8(x, y);
        }
    }
}

// ==================== MFMA ITM head (dots inline) ====================
__device__ __forceinline__ void stage_head(const ushort_t* __restrict__ TCB,
                                           const ushort_t* __restrict__ VCB,
                                           const int* __restrict__ neg, int isNeg,
                                           const ushort_t* __restrict__ W1T,
                                           ushort_t* As, ushort_t* Bs,
                                           int rowBase, int kc, int tid) {
    #pragma unroll
    for (int i = 0; i < 2; ++i) {                 // A: 64 rows x 64 k
        int idx = i * 256 + tid;
        int r = idx >> 3, c8 = idx & 7;
        const ushort_t* src;
        if (kc < 256) {
            src = TCB + (size_t)(rowBase + r) * DD + kc + c8 * 8;
        } else {
            int rr = isNeg ? neg[rowBase + r] : (rowBase + r);
            int cs = c8 ^ ((r ^ rr) & 7);          // re-key rr&7 -> r&7
            src = VCB + (size_t)rr * DD + (kc - 256) + cs * 8;
        }
        __builtin_amdgcn_global_load_lds(
            (const __attribute__((address_space(1))) uint32_t*)src,
            (__attribute__((address_space(3))) uint32_t*)(As + idx * 8), 16, 0, 0);
    }
    #pragma unroll
    for (int i = 0; i < 8; ++i) {                 // B: 256 cols x 64 k (W1T pre-swizzled)
        int idx = i * 256 + tid;
        int n = idx >> 3, c8 = idx & 7;
        __builtin_amdgcn_global_load_lds(
            (const __attribute__((address_space(1))) uint32_t*)(W1T + (size_t)n * 512 + kc + c8 * 8),
            (__attribute__((address_space(3))) uint32_t*)(Bs + idx * 8), 16, 0, 0);
    }
}

__global__ __launch_bounds__(256) void head2_kernel(const ushort_t* __restrict__ TCB,
                                                    const ushort_t* __restrict__ VCB,
                                                    const ushort_t* __restrict__ W1T,
                                                    const int* __restrict__ neg,
                                                    const float* __restrict__ tcf,
                                                    const float* __restrict__ vcf,
                                                    const float* __restrict__ W1,
                                                    const float* __restrict__ b1,
                                                    const float* __restrict__ W2,
                                                    const float* __restrict__ b2,
                                                    float* __restrict__ acc_out) {
    __shared__ ushort_t As[2][64 * 64];
    __shared__ ushort_t Bs[2][256 * 64];
    __shared__ float dot_l[64];
    __shared__ float logit_l[64];

    const int tid = threadIdx.x;
    const int rowBase = blockIdx.x * 64;
    const int isNeg = blockIdx.y;
    const int lane = tid & 63;
    const int wcv = tid >> 6;
    const int lo = lane & 15, hi = lane >> 4;
    const int lx = lo & 7;

    // inline dot feature (fp32 exact): 4 threads per row
    {
        int r = tid >> 2, quarter = tid & 3;
        int grow = rowBase + r;
        int vrow = isNeg ? neg[grow] : grow;
        const float4* tp = (const float4*)(tcf + (size_t)grow * DD + quarter * 64);
        const float4* vp = (const float4*)(vcf + (size_t)vrow * DD + quarter * 64);
        float sd = 0.f;
        #pragma unroll
        for (int j = 0; j < 16; j++) {
            float4 a = tp[j], v = vp[j];
            sd += a.x * v.x + a.y * v.y + a.z * v.z + a.w * v.w;
        }
        sd += __shfl_xor(sd, 1);
        sd += __shfl_xor(sd, 2);
        if (quarter == 0) dot_l[r] = sd;
        if (tid < 64) logit_l[tid] = 0.f;
    }

    f32x4 acc[4][4];
    #pragma unroll
    for (int m = 0; m < 4; m++)
        #pragma unroll
        for (int n = 0; n < 4; n++) acc[m][n] = (f32x4){0.f, 0.f, 0.f, 0.f};

    stage_head(TCB, VCB, neg, isNeg, W1T, As[0], Bs[0], rowBase, 0, tid);
    __syncthreads();

    for (int kt = 0; kt < 8; ++kt) {
        const int buf = kt & 1;
        if (kt < 7)
            stage_head(TCB, VCB, neg, isNeg, W1T, As[buf ^ 1], Bs[buf ^ 1], rowBase, (kt + 1) * 64, tid);
        #pragma unroll
        for (int ksl = 0; ksl < 2; ksl++) {
            const int ch = (((ksl << 2) | hi) ^ lx) * 8;
            bf16x8 a[4], b[4];
            #pragma unroll
            for (int m = 0; m < 4; m++)
                a[m] = *(const bf16x8*)&As[buf][(m * 16 + lo) * 64 + ch];
            #pragma unroll
            for (int n = 0; n < 4; n++)
                b[n] = *(const bf16x8*)&Bs[buf][(wcv * 64 + n * 16 + lo) * 64 + ch];
            #pragma unroll
            for (int m = 0; m < 4; m++)
                #pragma unroll
                for (int n = 0; n < 4; n++)
                    acc[m][n] = __builtin_amdgcn_mfma_f32_16x16x32_bf16(a[m], b[n], acc[m][n], 0, 0, 0);
        }
        __syncthreads();
    }

    float b1v[4], w5v[4], w2v[4];
    #pragma unroll
    for (int n = 0; n < 4; n++) {
        int cl = wcv * 64 + n * 16 + lo;
        b1v[n] = b1[cl];
        w5v[n] = W1[(size_t)512 * DD + cl];
        w2v[n] = W2[cl];
    }
    #pragma unroll
    for (int m = 0; m < 4; m++) {
        #pragma unroll
        for (int q = 0; q < 4; q++) {
            const int rl = m * 16 + hi * 4 + q;
            const float dt = dot_l[rl];
            float x = 0.f;
            #pragma unroll
            for (int n = 0; n < 4; n++) {
                float h = acc[m][n][q] + b1v[n] + dt * w5v[n];
                x += fmaxf(h, 0.f) * w2v[n];
            }
            #pragma unroll
            for (int off = 1; off < 16; off <<= 1) x += __shfl_xor(x, off);
            if (lo == 0) atomicAdd(&logit_l[rl], x);
        }
    }
    __syncthreads();

    if (tid < 64) {
        float x = logit_l[tid] + b2[0];
        float z = isNeg ? x : -x;                        // 1-sigmoid(x) = sigmoid(-x)
        float term = -logf(1.f / (1.f + expf(z)) + 1e-8f);
        #pragma unroll
        for (int off = 32; off; off >>= 1) term += __shfl_down(term, off);
        if (tid == 0) atomicAdd(acc_out, term);
    }
}

__global__ void finalize_kernel(const float* __restrict__ acc, float* __restrict__ out) {
    out[0] = acc[0] * (1.0f / (2.0f * (float)NB));
}

// ==================== launch ====================
extern "C" void kernel_launch(void* const* d_in, const int* in_sizes, int n_in,
                              void* d_out, int out_size, void* d_ws, size_t ws_size,
                              hipStream_t stream) {
    const float* vcross = (const float*)d_in[0];
    const float* tcross = (const float*)d_in[1];
    const float* vuni   = (const float*)d_in[2];
    const float* tuni   = (const float*)d_in[3];
    const float* W1     = (const float*)d_in[4];
    const float* b1     = (const float*)d_in[5];
    const float* W2     = (const float*)d_in[6];
    const float* b2     = (const float*)d_in[7];

    char* ws = (char*)d_ws;
    float* diag   = (float*)(ws + OFF_DIAG);
    int* neg      = (int*)(ws + OFF_NEG);
    int* band     = (int*)(ws + OFF_BAND);
    int* fbrows   = (int*)(ws + OFF_FBROWS);
    float* acc    = (float*)(ws + OFF_ACC);
    int* fbcount  = (int*)(ws + OFF_ACC + 4);
    unsigned long long* fbbest = (unsigned long long*)(ws + OFF_ACC + 8);
    ushort_t* w1t = (ushort_t*)(ws + OFF_W1T);
    ushort_t* tb  = (ushort_t*)(ws + OFF_TB);
    ushort_t* vb  = (ushort_t*)(ws + OFF_VB);

    hipMemsetAsync(ws + OFF_ACC, 0, 8 + 64 * 8, stream);   // acc + fbcount + fbbest[64]

    prep_uni_kernel<<<4096, 256, 0, stream>>>(tuni, vuni, tb, vb, diag, band);
    mine2_kernel<<<dim3(NB / 128, 16), 256, 0, stream>>>(tb, vb, diag, band);
    combine3_kernel<<<NB / 256, 256, 0, stream>>>(band, neg, fbrows, fbcount);
    fixup3_kernel<<<dim3(32, 64), 256, 0, stream>>>(tuni, vuni, fbrows, fbcount, fbbest);
    fixup_write_kernel<<<1, 64, 0, stream>>>(fbrows, fbcount, fbbest, neg);
    prep_head_kernel<<<2080, 256, 0, stream>>>(tcross, vcross, W1, tb, vb, w1t);
    head2_kernel<<<dim3(NB / 64, 2), 256, 0, stream>>>(tb, vb, w1t, neg, tcross, vcross,
                                                       W1, b1, W2, b2, acc);
    finalize_kernel<<<1, 1, 0, stream>>>(acc, (float*)d_out);
}

// Round 7
// 168.559 us; speedup vs baseline: 1.9384x; 1.1383x over previous
//
#include <hip/hip_runtime.h>
#include <stdint.h>

#define NB 8192
#define DD 256

typedef unsigned short ushort_t;
typedef __attribute__((ext_vector_type(8))) short bf16x8;
typedef __attribute__((ext_vector_type(4))) float f32x4;

// ==================== workspace layout ====================
#define OFF_DIAG   0          // f32[8192]
#define OFF_NEG    32768      // int[8192]
#define OFF_BAND   65536      // int[8192]
#define OFF_FBROWS 98304      // int[8192] (only first 64 used)
#define OFF_ACC    131072     // f32 acc @+0, int fbcount @+4, u64 fbbest[64] @+8  (520 B)
#define OFF_W1T    163840     // bf16[256][512]  (256 KB, swizzled)
#define OFF_TB     425984     // bf16[8192][256] (4 MB, swizzled)
#define OFF_VB     4620288    // bf16[8192][256] (4 MB, swizzled) -> end 8814592

__device__ __forceinline__ unsigned short f2bf(float x) {
    uint32_t u = __float_as_uint(x);
    return (unsigned short)((u + 0x7FFFu + ((u >> 16) & 1u)) >> 16);
}

__device__ __forceinline__ uint4 packbf8(float4 x, float4 y) {
    uint4 o;
    o.x = (uint32_t)f2bf(x.x) | ((uint32_t)f2bf(x.y) << 16);
    o.y = (uint32_t)f2bf(x.z) | ((uint32_t)f2bf(x.w) << 16);
    o.z = (uint32_t)f2bf(y.x) | ((uint32_t)f2bf(y.y) << 16);
    o.w = (uint32_t)f2bf(y.z) | ((uint32_t)f2bf(y.w) << 16);
    return o;
}

__device__ __forceinline__ unsigned fkey(float s) {
    unsigned u = __float_as_uint(s);
    return (u & 0x80000000u) ? ~u : (u | 0x80000000u);
}

// ---------------- prep_uni: cvt (swizzled), diag, band init, scalar zero-init ----------------
__global__ __launch_bounds__(256) void prep_uni_kernel(const float* __restrict__ t,
                                                       const float* __restrict__ v,
                                                       ushort_t* __restrict__ tb,
                                                       ushort_t* __restrict__ vb,
                                                       float* __restrict__ diag,
                                                       int* __restrict__ band,
                                                       uint32_t* __restrict__ zeroRegion) {
    const int b = blockIdx.x;
    if (b < 2048) {
        const float* in = (b < 1024) ? t : v;
        ushort_t* out = (b < 1024) ? tb : vb;
        int i = (b & 1023) * 256 + threadIdx.x;     // chunk id
        int row = i >> 5, cw = i & 31, kb = cw >> 3, c = cw & 7;
        int csrc = c ^ (row & 7);
        const float4* src = (const float4*)(in + (size_t)row * DD + kb * 64 + csrc * 8);
        ((uint4*)out)[i] = packbf8(src[0], src[1]);
    } else {
        if (b == 2048 && threadIdx.x < 130) zeroRegion[threadIdx.x] = 0;  // acc+fbcount+fbbest
        int row = (b - 2048) * 4 + (threadIdx.x >> 6);
        int lane = threadIdx.x & 63;
        float4 a = *(const float4*)(t + (size_t)row * DD + lane * 4);
        float4 bb = *(const float4*)(v + (size_t)row * DD + lane * 4);
        float s = a.x * bb.x + a.y * bb.y + a.z * bb.z + a.w * bb.w;
        #pragma unroll
        for (int off = 32; off; off >>= 1) s += __shfl_down(s, off);
        if (lane == 0) diag[row] = s;
        if (lane == 1) band[row] = 0x7F7F7F7F;
    }
}

// ---------------- mine3: A direct-to-reg, B LDS-dbuf, 128x128/block ----------------
__device__ __forceinline__ void stage_b(const ushort_t* __restrict__ VB, ushort_t* Bs,
                                        int colBase, int kc, int tid) {
    #pragma unroll
    for (int i = 0; i < 4; ++i) {
        int idx = i * 256 + tid;              // 0..1023
        int r = idx >> 3, c8 = idx & 7;       // source pre-swizzled -> linear copy
        __builtin_amdgcn_global_load_lds(
            (const __attribute__((address_space(1))) uint32_t*)(VB + (size_t)(colBase + r) * DD + kc + c8 * 8),
            (__attribute__((address_space(3))) uint32_t*)(Bs + idx * 8), 16, 0, 0);
    }
}

__global__ __launch_bounds__(256, 4) void mine3_kernel(const ushort_t* __restrict__ TB,
                                                       const ushort_t* __restrict__ VB,
                                                       const float* __restrict__ diag,
                                                       int* __restrict__ band) {
    __shared__ ushort_t Bs[2][128 * 64];       // 32 KB
    __shared__ float diag_s[128];

    const int tid = threadIdx.x;
    const int bid = blockIdx.x;
    const int rowBase = (bid >> 6) * 128;
    const int colBase = (bid & 63) * 128;
    const int lane = tid & 63;
    const int wave = tid >> 6;
    const int wr = wave >> 1, wc = wave & 1;   // 2x2 waves, 64x64 each
    const int lo = lane & 15, hi = lane >> 4;
    const int lx = lo & 7;

    if (tid < 128) diag_s[tid] = diag[rowBase + tid];

    f32x4 acc[4][4];
    #pragma unroll
    for (int m = 0; m < 4; m++)
        #pragma unroll
        for (int n = 0; n < 4; n++) acc[m][n] = (f32x4){0.f, 0.f, 0.f, 0.f};

    // A base: row = rowBase + wr*64 + m*16 + lo; (row&7)==(lo&7) since rowBase,wr*64,m*16 are mult of 8
    const ushort_t* Abase = TB + (size_t)(rowBase + wr * 64 + lo) * DD;

    stage_b(VB, Bs[0], colBase, 0, tid);
    __syncthreads();

    for (int kt = 0; kt < 4; ++kt) {
        const int buf = kt & 1;
        if (kt < 3)
            stage_b(VB, Bs[buf ^ 1], colBase, (kt + 1) * 64, tid);
        #pragma unroll
        for (int ksl = 0; ksl < 2; ksl++) {
            const int ch = (((ksl << 2) | hi) ^ lx) * 8;
            bf16x8 a[4], b[4];
            #pragma unroll
            for (int m = 0; m < 4; m++)
                a[m] = *(const bf16x8*)(Abase + (size_t)m * 16 * DD + kt * 64 + ch);
            #pragma unroll
            for (int n = 0; n < 4; n++)
                b[n] = *(const bf16x8*)&Bs[buf][(wc * 64 + n * 16 + lo) * 64 + ch];
            #pragma unroll
            for (int m = 0; m < 4; m++)
                #pragma unroll
                for (int n = 0; n < 4; n++)
                    acc[m][n] = __builtin_amdgcn_mfma_f32_16x16x32_bf16(a[m], b[n], acc[m][n], 0, 0, 0);
        }
        __syncthreads();
    }

    // epilogue (once per block): band-min; |s-(d-0.35)| < 0.15 <=> d-0.5 < s < d-0.2
    #pragma unroll
    for (int m = 0; m < 4; m++) {
        #pragma unroll
        for (int q = 0; q < 4; q++) {
            const int rl = wr * 64 + m * 16 + hi * 4 + q;
            const float c0 = diag_s[rl] - 0.35f;
            int bm = 0x7FFFFFFF;
            #pragma unroll
            for (int n = 0; n < 4; n++) {
                const float tt = acc[m][n][q] - c0;
                const int gcol = colBase + wc * 64 + n * 16 + lo;
                int cand = (fabsf(tt) < 0.15f) ? gcol : 0x7FFFFFFF;
                bm = min(bm, cand);
            }
            #pragma unroll
            for (int off = 1; off < 16; off <<= 1) bm = min(bm, __shfl_xor(bm, off));
            if (lo == 0 && bm != 0x7FFFFFFF)
                atomicMin(&band[rowBase + rl], bm);
        }
    }
}

// ---------------- combine: neg from band; collect fallback rows (cap 64) ----------------
__global__ __launch_bounds__(256) void combine3_kernel(const int* __restrict__ band,
                                                       int* __restrict__ neg,
                                                       int* __restrict__ fbrows,
                                                       int* __restrict__ fbcount) {
    int row = blockIdx.x * 256 + threadIdx.x;
    int v = band[row];
    if (v < NB) {
        neg[row] = v;
    } else {
        neg[row] = (row + 4096) & (NB - 1);     // valid placeholder (patched in prep_head)
        int i = atomicAdd(fbcount, 1);
        if (i < 64) fbrows[i] = row;
    }
}

// ---------------- fixup3: parallel off-diag argmax for empty-band rows ----------------
__global__ __launch_bounds__(256) void fixup3_kernel(const float* __restrict__ tuni,
                                                     const float* __restrict__ vuni,
                                                     const int* __restrict__ fbrows,
                                                     const int* __restrict__ fbcount,
                                                     unsigned long long* __restrict__ fbbest) {
    const int slot = blockIdx.y;
    const int count = min(fbcount[0], 64);
    if (slot >= count) return;
    const int row = fbrows[slot];
    const int tid = threadIdx.x;

    __shared__ float tL[DD];
    tL[tid] = tuni[(size_t)row * DD + tid];
    __syncthreads();

    const int col = blockIdx.x * 256 + tid;
    const float4* vr = (const float4*)(vuni + (size_t)col * DD);
    float d = 0.f;
    #pragma unroll 8
    for (int k4 = 0; k4 < 64; k4++) {
        float4 v = vr[k4];
        const float* tk = &tL[k4 * 4];
        d += v.x * tk[0] + v.y * tk[1] + v.z * tk[2] + v.w * tk[3];
    }
    if (col != row) {
        unsigned long long p = ((unsigned long long)fkey(d) << 32) | (unsigned)(NB - 1 - col);
        atomicMax(&fbbest[slot], p);
    }
}

// ---------------- prep_head: cvt tcross/vcross, W1T (swizzled), + fixup writeback ----------------
__global__ __launch_bounds__(256) void prep_head_kernel(const float* __restrict__ tcross,
                                                        const float* __restrict__ vcross,
                                                        const float* __restrict__ W1,
                                                        ushort_t* __restrict__ tb,
                                                        ushort_t* __restrict__ vb,
                                                        ushort_t* __restrict__ W1T,
                                                        const int* __restrict__ fbrows,
                                                        const int* __restrict__ fbcount,
                                                        const unsigned long long* __restrict__ fbbest,
                                                        int* __restrict__ neg) {
    const int b = blockIdx.x;
    const int tid = threadIdx.x;
    if (b < 2048) {
        const float* in = (b < 1024) ? tcross : vcross;
        ushort_t* out = (b < 1024) ? tb : vb;
        int i = (b & 1023) * 256 + tid;
        int row = i >> 5, cw = i & 31, kb = cw >> 3, c = cw & 7;
        int csrc = c ^ (row & 7);
        const float4* src = (const float4*)(in + (size_t)row * DD + kb * 64 + csrc * 8);
        ((uint4*)out)[i] = packbf8(src[0], src[1]);
    } else if (b < 2080) {
        // W1T[n][k] = bf16(W1[k][n]), chunk-swizzled by n&7 within each 64-k block
        __shared__ float Ls[64][68];
        int tt = b - 2048;                  // 0..31
        int kb = tt >> 2, nb = tt & 3;
        int r = tid >> 2, q4 = tid & 3;
        #pragma unroll
        for (int j = 0; j < 4; j++) {
            float4 x = *(const float4*)(W1 + (size_t)(kb * 64 + r) * DD + nb * 64 + q4 * 16 + j * 4);
            *(float4*)&Ls[r][q4 * 16 + j * 4] = x;
        }
        __syncthreads();
        int rn = tid >> 2, cq = (tid & 3) * 2;
        #pragma unroll
        for (int cc = 0; cc < 2; cc++) {
            int c = cq + cc;
            int csrc = c ^ (rn & 7);
            float4 x, y;
            x.x = Ls[csrc * 8 + 0][rn]; x.y = Ls[csrc * 8 + 1][rn];
            x.z = Ls[csrc * 8 + 2][rn]; x.w = Ls[csrc * 8 + 3][rn];
            y.x = Ls[csrc * 8 + 4][rn]; y.y = Ls[csrc * 8 + 5][rn];
            y.z = Ls[csrc * 8 + 6][rn]; y.w = Ls[csrc * 8 + 7][rn];
            *(uint4*)&W1T[(size_t)(nb * 64 + rn) * 512 + kb * 64 + c * 8] = packbf8(x, y);
        }
    } else {
        // fixup writeback (runs after fixup3 in stream order)
        if (tid < min(fbcount[0], 64))
            neg[fbrows[tid]] = NB - 1 - (int)(unsigned)(fbbest[tid] & 0xFFFFFFFFull);
    }
}

// ==================== MFMA ITM head (dots inline) ====================
__device__ __forceinline__ void stage_head(const ushort_t* __restrict__ TCB,
                                           const ushort_t* __restrict__ VCB,
                                           const int* __restrict__ neg, int isNeg,
                                           const ushort_t* __restrict__ W1T,
                                           ushort_t* As, ushort_t* Bs,
                                           int rowBase, int kc, int tid) {
    #pragma unroll
    for (int i = 0; i < 2; ++i) {                 // A: 64 rows x 64 k
        int idx = i * 256 + tid;
        int r = idx >> 3, c8 = idx & 7;
        const ushort_t* src;
        if (kc < 256) {
            src = TCB + (size_t)(rowBase + r) * DD + kc + c8 * 8;
        } else {
            int rr = isNeg ? neg[rowBase + r] : (rowBase + r);
            int cs = c8 ^ ((r ^ rr) & 7);          // re-key rr&7 -> r&7
            src = VCB + (size_t)rr * DD + (kc - 256) + cs * 8;
        }
        __builtin_amdgcn_global_load_lds(
            (const __attribute__((address_space(1))) uint32_t*)src,
            (__attribute__((address_space(3))) uint32_t*)(As + idx * 8), 16, 0, 0);
    }
    #pragma unroll
    for (int i = 0; i < 8; ++i) {                 // B: 256 cols x 64 k (W1T pre-swizzled)
        int idx = i * 256 + tid;
        int n = idx >> 3, c8 = idx & 7;
        __builtin_amdgcn_global_load_lds(
            (const __attribute__((address_space(1))) uint32_t*)(W1T + (size_t)n * 512 + kc + c8 * 8),
            (__attribute__((address_space(3))) uint32_t*)(Bs + idx * 8), 16, 0, 0);
    }
}

__global__ __launch_bounds__(256) void head2_kernel(const ushort_t* __restrict__ TCB,
                                                    const ushort_t* __restrict__ VCB,
                                                    const ushort_t* __restrict__ W1T,
                                                    const int* __restrict__ neg,
                                                    const float* __restrict__ tcf,
                                                    const float* __restrict__ vcf,
                                                    const float* __restrict__ W1,
                                                    const float* __restrict__ b1,
                                                    const float* __restrict__ W2,
                                                    const float* __restrict__ b2,
                                                    float* __restrict__ acc_out) {
    __shared__ ushort_t As[2][64 * 64];
    __shared__ ushort_t Bs[2][256 * 64];
    __shared__ float dot_l[64];
    __shared__ float logit_l[64];

    const int tid = threadIdx.x;
    const int rowBase = blockIdx.x * 64;
    const int isNeg = blockIdx.y;
    const int lane = tid & 63;
    const int wcv = tid >> 6;
    const int lo = lane & 15, hi = lane >> 4;
    const int lx = lo & 7;

    // inline dot feature (fp32 exact): 4 threads per row
    {
        int r = tid >> 2, quarter = tid & 3;
        int grow = rowBase + r;
        int vrow = isNeg ? neg[grow] : grow;
        const float4* tp = (const float4*)(tcf + (size_t)grow * DD + quarter * 64);
        const float4* vp = (const float4*)(vcf + (size_t)vrow * DD + quarter * 64);
        float sd = 0.f;
        #pragma unroll
        for (int j = 0; j < 16; j++) {
            float4 a = tp[j], v = vp[j];
            sd += a.x * v.x + a.y * v.y + a.z * v.z + a.w * v.w;
        }
        sd += __shfl_xor(sd, 1);
        sd += __shfl_xor(sd, 2);
        if (quarter == 0) dot_l[r] = sd;
        if (tid < 64) logit_l[tid] = 0.f;
    }

    f32x4 acc[4][4];
    #pragma unroll
    for (int m = 0; m < 4; m++)
        #pragma unroll
        for (int n = 0; n < 4; n++) acc[m][n] = (f32x4){0.f, 0.f, 0.f, 0.f};

    stage_head(TCB, VCB, neg, isNeg, W1T, As[0], Bs[0], rowBase, 0, tid);
    __syncthreads();

    for (int kt = 0; kt < 8; ++kt) {
        const int buf = kt & 1;
        if (kt < 7)
            stage_head(TCB, VCB, neg, isNeg, W1T, As[buf ^ 1], Bs[buf ^ 1], rowBase, (kt + 1) * 64, tid);
        #pragma unroll
        for (int ksl = 0; ksl < 2; ksl++) {
            const int ch = (((ksl << 2) | hi) ^ lx) * 8;
            bf16x8 a[4], b[4];
            #pragma unroll
            for (int m = 0; m < 4; m++)
                a[m] = *(const bf16x8*)&As[buf][(m * 16 + lo) * 64 + ch];
            #pragma unroll
            for (int n = 0; n < 4; n++)
                b[n] = *(const bf16x8*)&Bs[buf][(wcv * 64 + n * 16 + lo) * 64 + ch];
            #pragma unroll
            for (int m = 0; m < 4; m++)
                #pragma unroll
                for (int n = 0; n < 4; n++)
                    acc[m][n] = __builtin_amdgcn_mfma_f32_16x16x32_bf16(a[m], b[n], acc[m][n], 0, 0, 0);
        }
        __syncthreads();
    }

    float b1v[4], w5v[4], w2v[4];
    #pragma unroll
    for (int n = 0; n < 4; n++) {
        int cl = wcv * 64 + n * 16 + lo;
        b1v[n] = b1[cl];
        w5v[n] = W1[(size_t)512 * DD + cl];
        w2v[n] = W2[cl];
    }
    #pragma unroll
    for (int m = 0; m < 4; m++) {
        #pragma unroll
        for (int q = 0; q < 4; q++) {
            const int rl = m * 16 + hi * 4 + q;
            const float dt = dot_l[rl];
            float x = 0.f;
            #pragma unroll
            for (int n = 0; n < 4; n++) {
                float h = acc[m][n][q] + b1v[n] + dt * w5v[n];
                x += fmaxf(h, 0.f) * w2v[n];
            }
            #pragma unroll
            for (int off = 1; off < 16; off <<= 1) x += __shfl_xor(x, off);
            if (lo == 0) atomicAdd(&logit_l[rl], x);
        }
    }
    __syncthreads();

    if (tid < 64) {
        float x = logit_l[tid] + b2[0];
        float z = isNeg ? x : -x;                        // 1-sigmoid(x) = sigmoid(-x)
        float term = -logf(1.f / (1.f + expf(z)) + 1e-8f);
        #pragma unroll
        for (int off = 32; off; off >>= 1) term += __shfl_down(term, off);
        if (tid == 0) atomicAdd(acc_out, term);
    }
}

__global__ void finalize_kernel(const float* __restrict__ acc, float* __restrict__ out) {
    out[0] = acc[0] * (1.0f / (2.0f * (float)NB));
}

// ==================== launch ====================
extern "C" void kernel_launch(void* const* d_in, const int* in_sizes, int n_in,
                              void* d_out, int out_size, void* d_ws, size_t ws_size,
                              hipStream_t stream) {
    const float* vcross = (const float*)d_in[0];
    const float* tcross = (const float*)d_in[1];
    const float* vuni   = (const float*)d_in[2];
    const float* tuni   = (const float*)d_in[3];
    const float* W1     = (const float*)d_in[4];
    const float* b1     = (const float*)d_in[5];
    const float* W2     = (const float*)d_in[6];
    const float* b2     = (const float*)d_in[7];

    char* ws = (char*)d_ws;
    float* diag   = (float*)(ws + OFF_DIAG);
    int* neg      = (int*)(ws + OFF_NEG);
    int* band     = (int*)(ws + OFF_BAND);
    int* fbrows   = (int*)(ws + OFF_FBROWS);
    float* acc    = (float*)(ws + OFF_ACC);
    int* fbcount  = (int*)(ws + OFF_ACC + 4);
    unsigned long long* fbbest = (unsigned long long*)(ws + OFF_ACC + 8);
    ushort_t* w1t = (ushort_t*)(ws + OFF_W1T);
    ushort_t* tb  = (ushort_t*)(ws + OFF_TB);
    ushort_t* vb  = (ushort_t*)(ws + OFF_VB);

    prep_uni_kernel<<<4096, 256, 0, stream>>>(tuni, vuni, tb, vb, diag, band,
                                              (uint32_t*)(ws + OFF_ACC));
    mine3_kernel<<<4096, 256, 0, stream>>>(tb, vb, diag, band);
    combine3_kernel<<<NB / 256, 256, 0, stream>>>(band, neg, fbrows, fbcount);
    fixup3_kernel<<<dim3(32, 64), 256, 0, stream>>>(tuni, vuni, fbrows, fbcount, fbbest);
    prep_head_kernel<<<2081, 256, 0, stream>>>(tcross, vcross, W1, tb, vb, w1t,
                                               fbrows, fbcount, fbbest, neg);
    head2_kernel<<<dim3(NB / 64, 2), 256, 0, stream>>>(tb, vb, w1t, neg, tcross, vcross,
                                                       W1, b1, W2, b2, acc);
    finalize_kernel<<<1, 1, 0, stream>>>(acc, (float*)d_out);
}